// Round 9
// baseline (39.187 us; speedup 1.0000x reference)
//
#include <hip/hip_runtime.h>
#include <hip/hip_bf16.h>
#include <math.h>

#define NUM_POS 17
#define SEQ 8192
#define BATCH 64
#define H1 128
#define H2 64
#define NFRAG 38     // 16 (GEMM1) + 18 (GEMM2 incl bias) + 4 (GEMM3)
#define WT_U32 320   // u32 slots per window tile (306 data + 14 zero pad)

typedef __attribute__((ext_vector_type(8)))  short        s16x8;
typedef __attribute__((ext_vector_type(16))) float        f32x16;
typedef __attribute__((ext_vector_type(4)))  unsigned int u32x4;

// v_cvt_pk_bf16_f32: D[15:0]=bf16(S0), D[31:16]=bf16(S1), RNE.
static __device__ __forceinline__ unsigned cvtpk(float lo, float hi) {
    unsigned r;
    asm("v_cvt_pk_bf16_f32 %0, %1, %2" : "=v"(r) : "v"(lo), "v"(hi));
    return r;
}
static __device__ __forceinline__ unsigned pkrelu(float a, float b) {
    return cvtpk(fmaxf(a, 0.0f), fmaxf(b, 0.0f));
}
static __device__ __forceinline__ f32x16 zero16() {
    f32x16 z;
    #pragma unroll
    for (int i = 0; i < 16; ++i) z[i] = 0.0f;
    return z;
}

// prep: 38 MFMA A-fragments frag-packed: Wp[frag][lane][8] bf16 (1KB/frag).
//  frags 0..15 : GEMM1, id=hf*4+kk. Slot s=kk*16+hi*8+j maps to the 18-padded
//                window layout: r=s/18, f=s%18; r<3 && f<17 -> W1[(r*17+f)][h];
//                s==53 -> b1[h] (row-2 pad slot, stored as 1.0 on the B side).
//  frags 16..33: GEMM2, id=16+kk9*2+f. kk9<8: k-permuted W2^T; kk9==8: b2 bias col.
//  frags 34..37: GEMM3, id=34+kk. Row 0 = W3 permuted to C2' order, rows 1..31 = 0.
__global__ void prep_kernel(const float* __restrict__ W1, const float* __restrict__ b1,
                            const float* __restrict__ W2, const float* __restrict__ b2,
                            const float* __restrict__ W3,
                            __hip_bfloat16* __restrict__ Wp) {
    int idx = blockIdx.x * 256 + threadIdx.x;
    if (idx >= NFRAG * 512) return;
    int fragid = idx >> 9;
    int lane   = (idx >> 3) & 63;
    int j      = idx & 7;
    int ml = lane & 31, hi = lane >> 5;
    float v = 0.0f;
    if (fragid < 16) {
        int hf = fragid >> 2, kk = fragid & 3;
        int s = kk * 16 + hi * 8 + j;
        int h = hf * 32 + ml;
        int r = s / 18, f = s - 18 * r;
        if (r < 3) {
            if (f < 17) v = W1[(r * 17 + f) * H1 + h];
            else if (s == 53) v = b1[h];
        }
    } else if (fragid < 34) {
        int g = fragid - 16;
        int kk9 = g >> 1, f = g & 1;
        int h2 = f * 32 + ml;
        if (kk9 < 8) {
            int k = kk9 * 16 + hi * 8 + j;
            int kk = k >> 4, hb = (k >> 3) & 1, jj = k & 7;
            int hperm = (kk & 3) * 32 + 8 * (((kk >> 2) << 1) | (jj >> 2)) + (jj & 3) + 4 * hb;
            v = W2[hperm * H2 + h2];
        } else {
            v = (hi == 0 && j == 0) ? b2[h2] : 0.0f;  // k==128 bias column
        }
    } else {
        int kk = fragid - 34;
        if (ml == 0) {
            int k = kk * 16 + hi * 8 + j;
            int kk2 = k >> 4, hb = (k >> 3) & 1, jj = k & 7;
            int f = kk2 & 1;
            int r = 8 * (kk2 >> 1) + jj;
            int h2 = 32 * f + (r & 3) + 8 * (r >> 2) + 4 * hb;
            v = W3[h2];
        }
    }
    Wp[idx] = __float2bfloat16(v);
}

// main: 2048 blocks x 4 waves; each wave computes 2 tiles of 32 rows,
// INTERLEAVED so each weight-fragment ds_read_b128 feeds both tiles' MFMAs.
// LDS 48KB -> 3 blocks/CU; VGPR cap 168 (3 waves/SIMD).
__global__ __launch_bounds__(256, 3)
void lpe_mfma_kernel(const float* __restrict__ pos,
                     const __hip_bfloat16* __restrict__ Wp,
                     const float* __restrict__ b3,
                     float* __restrict__ out) {
    __shared__ __hip_bfloat16 wl[NFRAG * 512];   // 38912 B
    __shared__ unsigned sw[8 * WT_U32];          // 10240 B  (total 49152 B)

    const int tid  = threadIdx.x;
    const int wid  = tid >> 6;       // 0..3
    const int lane = tid & 63;
    const int ml   = lane & 31;
    const int hi   = lane >> 5;

    const int batch = blockIdx.x >> 5;   // 64 batches x 32 blocks
    const int blk   = blockIdx.x & 31;
    const int wrow0 = blk * 256 + wid * 64;

    // ---- stage weights global -> LDS (coalesced 16B copies) ----
    {
        const u32x4* src = reinterpret_cast<const u32x4*>(Wp);
        u32x4* dst = reinterpret_cast<u32x4*>(wl);
        #pragma unroll
        for (int it = 0; it < 10; ++it) {
            int i = it * 256 + tid;
            if (i < NFRAG * 512 * 2 / 16) dst[i] = src[i];
        }
    }

    // ---- stage 2 window tiles per wave as packed bf16, 18-elem padded rows ----
    // u32 p (p=0..305): R=p/9, jj=p%9; jj<8 -> (src[R*17+2jj], src[R*17+2jj+1]);
    // jj==8 -> (src[R*17+16], 1.0).  u32 306..319 zeroed.
    #pragma unroll
    for (int t = 0; t < 2; ++t) {
        unsigned* dst = sw + (wid * 2 + t) * WT_U32;
        const int srow0 = wrow0 + t * 32;
        const float* src = pos + ((size_t)batch * SEQ + srow0) * NUM_POS;
        const int lim = (SEQ - srow0) * NUM_POS;
        #pragma unroll
        for (int it = 0; it < 5; ++it) {
            int p = it * 64 + lane;
            if (p < 306) {
                int R = p / 9;
                int jj = p - 9 * R;
                int i0 = R * NUM_POS + 2 * jj;
                float a = (i0 < lim) ? src[i0] : 0.0f;
                float b;
                if (jj < 8) b = (i0 + 1 < lim) ? src[i0 + 1] : 0.0f;
                else        b = 1.0f;   // row pad slot = 1.0 (bias carrier)
                dst[p] = cvtpk(a, b);
            }
        }
        if (lane < WT_U32 - 306) dst[306 + lane] = 0u;
    }
    __syncthreads();

    const float b3v = b3[0];

    // constant bias B-fragment for GEMM2's k=128 step
    u32x4 b2cu; b2cu[0] = (hi == 0) ? 0x3f80u : 0u; b2cu[1] = 0u; b2cu[2] = 0u; b2cu[3] = 0u;
    const s16x8 B2C = __builtin_bit_cast(s16x8, b2cu);

    const __hip_bfloat16* wlb = wl + lane * 8;  // lane-linear frag base

    // ---- B1 fragments for both tiles (straight u32 reads, stride-9: bank-free) ----
    u32x4 B1u0[4], B1u1[4];
    {
        const unsigned* wb0 = sw + (wid * 2 + 0) * WT_U32 + ml * 9 + 4 * hi;
        const unsigned* wb1 = sw + (wid * 2 + 1) * WT_U32 + ml * 9 + 4 * hi;
        #pragma unroll
        for (int kk = 0; kk < 4; ++kk) {
            u32x4 u0, u1;
            #pragma unroll
            for (int c = 0; c < 4; ++c) {
                u0[c] = wb0[8 * kk + c];
                u1[c] = wb1[8 * kk + c];
            }
            B1u0[kk] = u0;
            B1u1[kk] = u1;
        }
    }

    // ---- GEMM1' interleaved: per hf, one A-frag read feeds both tiles ----
    unsigned pk1[2][4][8];
    #pragma unroll
    for (int hf = 0; hf < 4; ++hf) {
        f32x16 c0 = zero16(), c1 = zero16();
        #pragma unroll
        for (int kk = 0; kk < 4; ++kk) {
            s16x8 a = *reinterpret_cast<const s16x8*>(wlb + (hf * 4 + kk) * 512);
            c0 = __builtin_amdgcn_mfma_f32_32x32x16_bf16(
                a, __builtin_bit_cast(s16x8, B1u0[kk]), c0, 0, 0, 0);
            c1 = __builtin_amdgcn_mfma_f32_32x32x16_bf16(
                a, __builtin_bit_cast(s16x8, B1u1[kk]), c1, 0, 0, 0);
        }
        #pragma unroll
        for (int j = 0; j < 8; ++j) {
            pk1[0][hf][j] = pkrelu(c0[2 * j], c0[2 * j + 1]);
            pk1[1][hf][j] = pkrelu(c1[2 * j], c1[2 * j + 1]);
        }
    }

    // ---- GEMM2' interleaved: per (kk,f) A-frag read feeds both tiles ----
    f32x16 a20a = zero16(), a20b = zero16();   // tile0: f=0, f=1
    f32x16 a21a = zero16(), a21b = zero16();   // tile1: f=0, f=1
    #pragma unroll
    for (int kk = 0; kk < 8; ++kk) {
        const int hf = kk & 3;
        const int jb = (kk >> 2) * 4;
        u32x4 bu0, bu1;
        #pragma unroll
        for (int c = 0; c < 4; ++c) {
            bu0[c] = pk1[0][hf][jb + c];
            bu1[c] = pk1[1][hf][jb + c];
        }
        const s16x8 bf0 = __builtin_bit_cast(s16x8, bu0);
        const s16x8 bf1 = __builtin_bit_cast(s16x8, bu1);
        s16x8 af0 = *reinterpret_cast<const s16x8*>(wlb + (16 + kk * 2 + 0) * 512);
        s16x8 af1 = *reinterpret_cast<const s16x8*>(wlb + (16 + kk * 2 + 1) * 512);
        a20a = __builtin_amdgcn_mfma_f32_32x32x16_bf16(af0, bf0, a20a, 0, 0, 0);
        a21a = __builtin_amdgcn_mfma_f32_32x32x16_bf16(af0, bf1, a21a, 0, 0, 0);
        a20b = __builtin_amdgcn_mfma_f32_32x32x16_bf16(af1, bf0, a20b, 0, 0, 0);
        a21b = __builtin_amdgcn_mfma_f32_32x32x16_bf16(af1, bf1, a21b, 0, 0, 0);
    }
    {   // b2 bias k-step (constant B-fragment, shared A-frags)
        s16x8 af0 = *reinterpret_cast<const s16x8*>(wlb + (16 + 16 + 0) * 512);
        s16x8 af1 = *reinterpret_cast<const s16x8*>(wlb + (16 + 16 + 1) * 512);
        a20a = __builtin_amdgcn_mfma_f32_32x32x16_bf16(af0, B2C, a20a, 0, 0, 0);
        a21a = __builtin_amdgcn_mfma_f32_32x32x16_bf16(af0, B2C, a21a, 0, 0, 0);
        a20b = __builtin_amdgcn_mfma_f32_32x32x16_bf16(af1, B2C, a20b, 0, 0, 0);
        a21b = __builtin_amdgcn_mfma_f32_32x32x16_bf16(af1, B2C, a21b, 0, 0, 0);
    }

    // ---- relu+pack acc2 -> pk2 (acc2 dies) ----
    unsigned pk20[2][8], pk21[2][8];
    #pragma unroll
    for (int j = 0; j < 8; ++j) {
        pk20[0][j] = pkrelu(a20a[2 * j], a20a[2 * j + 1]);
        pk20[1][j] = pkrelu(a20b[2 * j], a20b[2 * j + 1]);
        pk21[0][j] = pkrelu(a21a[2 * j], a21a[2 * j + 1]);
        pk21[1][j] = pkrelu(a21b[2 * j], a21b[2 * j + 1]);
    }

    // ---- GEMM3' + epilogue, per tile (A-frags re-read; only 8 extra b128) ----
    #pragma unroll
    for (int t = 0; t < 2; ++t) {
        f32x16 acc3a = zero16(), acc3b = zero16();
        #pragma unroll
        for (int kk = 0; kk < 4; ++kk) {
            const int f  = kk & 1;
            const int jb = (kk >> 1) * 4;
            u32x4 bu;
            #pragma unroll
            for (int c = 0; c < 4; ++c)
                bu[c] = t ? pk21[f][jb + c] : pk20[f][jb + c];
            const s16x8 bfrag = __builtin_bit_cast(s16x8, bu);
            s16x8 a = *reinterpret_cast<const s16x8*>(wlb + (34 + kk) * 512);
            if (f == 0)
                acc3a = __builtin_amdgcn_mfma_f32_32x32x16_bf16(a, bfrag, acc3a, 0, 0, 0);
            else
                acc3b = __builtin_amdgcn_mfma_f32_32x32x16_bf16(a, bfrag, acc3b, 0, 0, 0);
        }
        if (hi == 0) {
            const int grow = wrow0 + t * 32 + ml;
            if (grow < SEQ - 2) {
                float v = acc3a[0] + acc3b[0] + b3v;
                out[(size_t)batch * (SEQ - 2) + grow] = 1.0f / (1.0f + __expf(-v));
            }
        }
    }
}

extern "C" void kernel_launch(void* const* d_in, const int* in_sizes, int n_in,
                              void* d_out, int out_size, void* d_ws, size_t ws_size,
                              hipStream_t stream) {
    const float* pos = (const float*)d_in[0];
    const float* W1  = (const float*)d_in[1];
    const float* b1  = (const float*)d_in[2];
    const float* W2  = (const float*)d_in[3];
    const float* b2  = (const float*)d_in[4];
    const float* W3  = (const float*)d_in[5];
    const float* b3  = (const float*)d_in[6];
    float* out = (float*)d_out;

    __hip_bfloat16* Wp = (__hip_bfloat16*)d_ws;  // 38 frags x 1KB = 38912 B

    prep_kernel<<<(NFRAG * 512 + 255) / 256, 256, 0, stream>>>(W1, b1, W2, b2, W3, Wp);

    // 64 batches x 32 blocks; each block = 4 waves x 2 tiles x 32 rows = 256 rows
    lpe_mfma_kernel<<<BATCH * 32, 256, 0, stream>>>(pos, Wp, b3, out);
}

// Round 10
// 32.881 us; speedup vs baseline: 1.1918x; 1.1918x over previous
//
#include <hip/hip_runtime.h>
#include <hip/hip_bf16.h>
#include <math.h>

#define NUM_POS 17
#define SEQ 8192
#define BATCH 64
#define H1 128
#define H2 64
#define NFRAG 38     // 16 (GEMM1) + 18 (GEMM2 incl bias) + 4 (GEMM3)
#define WT_U32 320   // u32 slots per window tile (306 data + 14 zero pad)

typedef __attribute__((ext_vector_type(8)))  short        s16x8;
typedef __attribute__((ext_vector_type(16))) float        f32x16;
typedef __attribute__((ext_vector_type(4)))  unsigned int u32x4;

// v_cvt_pk_bf16_f32: D[15:0]=bf16(S0), D[31:16]=bf16(S1), RNE.
static __device__ __forceinline__ unsigned cvtpk(float lo, float hi) {
    unsigned r;
    asm("v_cvt_pk_bf16_f32 %0, %1, %2" : "=v"(r) : "v"(lo), "v"(hi));
    return r;
}
static __device__ __forceinline__ unsigned pkrelu(float a, float b) {
    return cvtpk(fmaxf(a, 0.0f), fmaxf(b, 0.0f));
}
static __device__ __forceinline__ f32x16 zero16() {
    f32x16 z;
    #pragma unroll
    for (int i = 0; i < 16; ++i) z[i] = 0.0f;
    return z;
}

// prep: 38 MFMA A-fragments frag-packed: Wp[frag][lane][8] bf16 (1KB/frag).
//  frags 0..15 : GEMM1, id=hf*4+kk. Slot s=kk*16+hi*8+j maps to the 18-padded
//                window layout: r=s/18, f=s%18; r<3 && f<17 -> W1[(r*17+f)][h];
//                s==53 -> b1[h] (row-2 pad slot, stored as 1.0 on the B side).
//  frags 16..33: GEMM2, id=16+kk9*2+f. kk9<8: k-permuted W2^T; kk9==8: b2 bias col.
//  frags 34..37: GEMM3, id=34+kk. Row 0 = W3 permuted to C2' order, rows 1..31 = 0.
__global__ void prep_kernel(const float* __restrict__ W1, const float* __restrict__ b1,
                            const float* __restrict__ W2, const float* __restrict__ b2,
                            const float* __restrict__ W3,
                            __hip_bfloat16* __restrict__ Wp) {
    int idx = blockIdx.x * 256 + threadIdx.x;
    if (idx >= NFRAG * 512) return;
    int fragid = idx >> 9;
    int lane   = (idx >> 3) & 63;
    int j      = idx & 7;
    int ml = lane & 31, hi = lane >> 5;
    float v = 0.0f;
    if (fragid < 16) {
        int hf = fragid >> 2, kk = fragid & 3;
        int s = kk * 16 + hi * 8 + j;
        int h = hf * 32 + ml;
        int r = s / 18, f = s - 18 * r;
        if (r < 3) {
            if (f < 17) v = W1[(r * 17 + f) * H1 + h];
            else if (s == 53) v = b1[h];
        }
    } else if (fragid < 34) {
        int g = fragid - 16;
        int kk9 = g >> 1, f = g & 1;
        int h2 = f * 32 + ml;
        if (kk9 < 8) {
            int k = kk9 * 16 + hi * 8 + j;
            int kk = k >> 4, hb = (k >> 3) & 1, jj = k & 7;
            int hperm = (kk & 3) * 32 + 8 * (((kk >> 2) << 1) | (jj >> 2)) + (jj & 3) + 4 * hb;
            v = W2[hperm * H2 + h2];
        } else {
            v = (hi == 0 && j == 0) ? b2[h2] : 0.0f;  // k==128 bias column
        }
    } else {
        int kk = fragid - 34;
        if (ml == 0) {
            int k = kk * 16 + hi * 8 + j;
            int kk2 = k >> 4, hb = (k >> 3) & 1, jj = k & 7;
            int f = kk2 & 1;
            int r = 8 * (kk2 >> 1) + jj;
            int h2 = 32 * f + (r & 3) + 8 * (r >> 2) + 4 * hb;
            v = W3[h2];
        }
    }
    Wp[idx] = __float2bfloat16(v);
}

// stage one 32-row window tile (34 rows x 17 f32) as packed bf16 into a
// wave-private LDS slot (18-elem padded rows; pad slot carries 1.0 = bias).
static __device__ __forceinline__ void stage_tile(unsigned* dst,
                                                  const float* __restrict__ src,
                                                  int lim, int lane) {
    #pragma unroll
    for (int it = 0; it < 5; ++it) {
        int p = it * 64 + lane;
        if (p < 306) {
            int R = p / 9;
            int jj = p - 9 * R;
            int i0 = R * NUM_POS + 2 * jj;
            float a = (i0 < lim) ? src[i0] : 0.0f;
            float b;
            if (jj < 8) b = (i0 + 1 < lim) ? src[i0 + 1] : 0.0f;
            else        b = 1.0f;   // row pad slot = 1.0 (bias carrier)
            dst[p] = cvtpk(a, b);
        }
    }
    if (lane < WT_U32 - 306) dst[306 + lane] = 0u;
}

// main: 512 blocks x 8 waves x 4 tiles x 32 rows = 524288 rows.
// Weights staged ONCE per block (2 blocks/CU, all co-resident -> zero churn).
// Window slots (2/wave, wave-private) re-staged for pair 1 after pair 0's
// B1 reads; no barriers needed beyond the single weights barrier.
__global__ __launch_bounds__(512, 4)
void lpe_mfma_kernel(const float* __restrict__ pos,
                     const __hip_bfloat16* __restrict__ Wp,
                     const float* __restrict__ b3,
                     float* __restrict__ out) {
    __shared__ __hip_bfloat16 wl[NFRAG * 512];   // 38912 B
    __shared__ unsigned sw[16 * WT_U32];         // 20480 B  (total 59392 B)

    const int tid  = threadIdx.x;
    const int wid  = tid >> 6;       // 0..7
    const int lane = tid & 63;
    const int ml   = lane & 31;
    const int hi   = lane >> 5;

    const int batch = blockIdx.x >> 3;   // 64 batches x 8 blocks
    const int blk   = blockIdx.x & 7;
    const int wrow0 = blk * 1024 + wid * 128;   // 4 tiles x 32 rows per wave

    const float* posb = pos + (size_t)batch * SEQ * NUM_POS;

    // ---- stage weights global -> LDS (coalesced 16B copies, 512 threads) ----
    {
        const u32x4* src = reinterpret_cast<const u32x4*>(Wp);
        u32x4* dst = reinterpret_cast<u32x4*>(wl);
        #pragma unroll
        for (int it = 0; it < 5; ++it) {
            int i = it * 512 + tid;
            if (i < NFRAG * 512 * 2 / 16) dst[i] = src[i];
        }
    }

    // ---- stage pair-0 window tiles (wave-private slots) ----
    #pragma unroll
    for (int t = 0; t < 2; ++t) {
        const int srow0 = wrow0 + t * 32;
        stage_tile(sw + (wid * 2 + t) * WT_U32,
                   posb + (size_t)srow0 * NUM_POS,
                   (SEQ - srow0) * NUM_POS, lane);
    }
    __syncthreads();

    const float b3v = b3[0];

    // constant bias B-fragment for GEMM2's k=128 step
    u32x4 b2cu; b2cu[0] = (hi == 0) ? 0x3f80u : 0u; b2cu[1] = 0u; b2cu[2] = 0u; b2cu[3] = 0u;
    const s16x8 B2C = __builtin_bit_cast(s16x8, b2cu);

    const __hip_bfloat16* wlb = wl + lane * 8;  // lane-linear frag base

    #pragma unroll 1
    for (int pair = 0; pair < 2; ++pair) {
        #pragma unroll 1
        for (int t = 0; t < 2; ++t) {
            const int srow0 = wrow0 + pair * 64 + t * 32;
            const unsigned* wb = sw + (wid * 2 + t) * WT_U32 + ml * 9 + 4 * hi;

            // ---- B1 fragments: 4 x u32x4 straight from LDS ----
            u32x4 B1u[4];
            #pragma unroll
            for (int kk = 0; kk < 4; ++kk) {
                u32x4 u;
                u[0] = wb[8 * kk + 0];
                u[1] = wb[8 * kk + 1];
                u[2] = wb[8 * kk + 2];
                u[3] = wb[8 * kk + 3];
                B1u[kk] = u;
            }

            // ---- restage this slot with the pair-1 tile (slot is dead after
            //      the B1u reads above; same-wave DS ordering guarantees
            //      read-before-write; load latency hides under GEMM2/3) ----
            if (pair == 0) {
                const int srow1 = srow0 + 64;
                stage_tile((unsigned*)(sw + (wid * 2 + t) * WT_U32),
                           posb + (size_t)srow1 * NUM_POS,
                           (SEQ - srow1) * NUM_POS, lane);
            }

            // ---- GEMM1' as two hf-pairs, relu-packed immediately ----
            unsigned pk1[4][8];
            #pragma unroll
            for (int hp = 0; hp < 2; ++hp) {
                f32x16 a1a = zero16(), a1b = zero16();
                #pragma unroll
                for (int kk = 0; kk < 4; ++kk) {
                    s16x8 aa = *reinterpret_cast<const s16x8*>(
                        wlb + ((2 * hp + 0) * 4 + kk) * 512);
                    a1a = __builtin_amdgcn_mfma_f32_32x32x16_bf16(
                        aa, __builtin_bit_cast(s16x8, B1u[kk]), a1a, 0, 0, 0);
                    s16x8 ab = *reinterpret_cast<const s16x8*>(
                        wlb + ((2 * hp + 1) * 4 + kk) * 512);
                    a1b = __builtin_amdgcn_mfma_f32_32x32x16_bf16(
                        ab, __builtin_bit_cast(s16x8, B1u[kk]), a1b, 0, 0, 0);
                }
                #pragma unroll
                for (int j = 0; j < 8; ++j) {
                    pk1[2 * hp + 0][j] = pkrelu(a1a[2 * j], a1a[2 * j + 1]);
                    pk1[2 * hp + 1][j] = pkrelu(a1b[2 * j], a1b[2 * j + 1]);
                }
            }

            // ---- GEMM2': B-frag for step kk = pk1[kk&3][4*(kk>>2) .. +3] ----
            f32x16 acc2[2];
            acc2[0] = zero16(); acc2[1] = zero16();
            #pragma unroll
            for (int kk = 0; kk < 8; ++kk) {
                const int hf = kk & 3;
                const int jb = (kk >> 2) * 4;
                u32x4 bu;
                bu[0] = pk1[hf][jb + 0];
                bu[1] = pk1[hf][jb + 1];
                bu[2] = pk1[hf][jb + 2];
                bu[3] = pk1[hf][jb + 3];
                const s16x8 bfrag = __builtin_bit_cast(s16x8, bu);
                #pragma unroll
                for (int f = 0; f < 2; ++f) {
                    s16x8 a = *reinterpret_cast<const s16x8*>(
                        wlb + (16 + kk * 2 + f) * 512);
                    acc2[f] = __builtin_amdgcn_mfma_f32_32x32x16_bf16(a, bfrag, acc2[f], 0, 0, 0);
                }
            }
            #pragma unroll
            for (int f = 0; f < 2; ++f) {
                s16x8 a = *reinterpret_cast<const s16x8*>(
                    wlb + (16 + 8 * 2 + f) * 512);
                acc2[f] = __builtin_amdgcn_mfma_f32_32x32x16_bf16(a, B2C, acc2[f], 0, 0, 0);
            }

            // ---- relu+pack acc2 -> pk2 ----
            unsigned pk2[2][8];
            #pragma unroll
            for (int f = 0; f < 2; ++f)
                #pragma unroll
                for (int j = 0; j < 8; ++j)
                    pk2[f][j] = pkrelu(acc2[f][2 * j], acc2[f][2 * j + 1]);

            // ---- GEMM3' as two independent 2-chains ----
            f32x16 acc3a = zero16(), acc3b = zero16();
            #pragma unroll
            for (int kk = 0; kk < 4; ++kk) {
                const int f  = kk & 1;
                const int jb = (kk >> 1) * 4;
                u32x4 bu;
                bu[0] = pk2[f][jb + 0];
                bu[1] = pk2[f][jb + 1];
                bu[2] = pk2[f][jb + 2];
                bu[3] = pk2[f][jb + 3];
                const s16x8 bfrag = __builtin_bit_cast(s16x8, bu);
                s16x8 a = *reinterpret_cast<const s16x8*>(wlb + (34 + kk) * 512);
                if (f == 0)
                    acc3a = __builtin_amdgcn_mfma_f32_32x32x16_bf16(a, bfrag, acc3a, 0, 0, 0);
                else
                    acc3b = __builtin_amdgcn_mfma_f32_32x32x16_bf16(a, bfrag, acc3b, 0, 0, 0);
            }

            // ---- epilogue: sigmoid + store (hi=0 lanes hold D row 0) ----
            if (hi == 0) {
                const int grow = srow0 + ml;
                if (grow < SEQ - 2) {
                    float v = acc3a[0] + acc3b[0] + b3v;
                    out[(size_t)batch * (SEQ - 2) + grow] = 1.0f / (1.0f + __expf(-v));
                }
            }
        }
    }
}

extern "C" void kernel_launch(void* const* d_in, const int* in_sizes, int n_in,
                              void* d_out, int out_size, void* d_ws, size_t ws_size,
                              hipStream_t stream) {
    const float* pos = (const float*)d_in[0];
    const float* W1  = (const float*)d_in[1];
    const float* b1  = (const float*)d_in[2];
    const float* W2  = (const float*)d_in[3];
    const float* b2  = (const float*)d_in[4];
    const float* W3  = (const float*)d_in[5];
    const float* b3  = (const float*)d_in[6];
    float* out = (float*)d_out;

    __hip_bfloat16* Wp = (__hip_bfloat16*)d_ws;  // 38 frags x 1KB = 38912 B

    prep_kernel<<<(NFRAG * 512 + 255) / 256, 256, 0, stream>>>(W1, b1, W2, b2, W3, Wp);

    // 64 batches x 8 blocks; each block = 8 waves x 4 tiles x 32 rows = 1024 rows
    lpe_mfma_kernel<<<BATCH * 8, 512, 0, stream>>>(pos, Wp, b3, out);
}